// Round 4
// baseline (425.274 us; speedup 1.0000x reference)
//
#include <hip/hip_runtime.h>
#include <math.h>

// Problem constants (fixed by reference).
#define TOKENS      16384     // 8 * 2048
#define HIDDEN_DIM  2048
#define EXPERTS     64
#define CAPSLOT     1024      // per-expert list cap; counts ~Binom(16384,1/64)=256±16
#define EXPERT_CAPACITY 512   // 2 * ceil(16384/64)

#define NKC     4             // k-split chunks
#define KCHUNK  512           // k per block (NKC*KCHUNK = HIDDEN_DIM)
#define KSUB    64            // staged k sub-tile
#define XPITCH  65            // LDS row pitch (stride-65 -> conflict-free b32)

// ---------------------------------------------------------------------------
// K1: partial logits GEMM, W from SGPRs (wave-uniform expert slice).
// Block = 128 threads = 2 waves (expert halves 0-31 / 32-63) sharing one
// x tile. lane = token (64 tokens/block), 32 fp32 accumulators per lane.
// x staged coalesced -> LDS (pitch 65, double buffer), read as b32 (no
// bank conflicts). W row slice is wave-uniform -> s_load, zero vector cost.
// ---------------------------------------------------------------------------
__global__ __launch_bounds__(128) void k_logits_partial(
    const float* __restrict__ x, const float* __restrict__ W,
    float* __restrict__ partial)              // [NKC][TOKENS][EXPERTS]
{
    __shared__ float xs[2][64 * XPITCH];      // 2 x 16.64 KB

    const int tid  = threadIdx.x;             // 0..127
    const int lane = tid & 63;                // token lane
    const int eh   = __builtin_amdgcn_readfirstlane(tid >> 6);  // expert half
    const int tg   = blockIdx.x & 255;        // token group
    const int kc   = blockIdx.x >> 8;         // k chunk (0..3)
    const int t0   = tg * 64;
    const int k0   = kc * KCHUNK;
    const int e0   = eh * 32;

    float acc[32];
    #pragma unroll
    for (int e = 0; e < 32; ++e) acc[e] = 0.f;

    // stage x[t0..t0+64)[ks..ks+KSUB) into xs[b], coalesced (256 B rows).
    auto stage = [&](int ks, int b) {
        #pragma unroll
        for (int i = 0; i < 8; ++i) {
            const int f   = i * 128 + tid;    // float4 index, 0..1023
            const int row = f >> 4;           // token row 0..63
            const int c4  = f & 15;           // float4 within row (16 = 64 k)
            float4 v = *(const float4*)(x + (size_t)(t0 + row) * HIDDEN_DIM
                                          + ks + c4 * 4);
            float* d = &xs[b][row * XPITCH + c4 * 4];
            d[0] = v.x; d[1] = v.y; d[2] = v.z; d[3] = v.w;
        }
    };

    stage(k0, 0);
    __syncthreads();

    for (int s = 0; s < KCHUNK / KSUB; ++s) {             // 8 sub-tiles
        if (s + 1 < KCHUNK / KSUB) stage(k0 + (s + 1) * KSUB, (s + 1) & 1);

        const float* xrow = &xs[s & 1][lane * XPITCH];
        const float* wbase = W + (size_t)(k0 + s * KSUB) * EXPERTS + e0;

        #pragma unroll 4
        for (int k = 0; k < KSUB; ++k) {
            const float xv = xrow[k];                      // ds_read_b32, 2/bank
            const float* wr = wbase + (size_t)k * EXPERTS; // wave-uniform
            #pragma unroll
            for (int e = 0; e < 32; ++e)
                acc[e] = fmaf(xv, wr[e], acc[e]);          // v_fmac w/ SGPR W
        }
        __syncthreads();
    }

    float* prow = partial + ((size_t)kc * TOKENS + t0 + lane) * EXPERTS + e0;
    #pragma unroll
    for (int e = 0; e < 32; e += 4)
        *(float4*)(prow + e) = make_float4(acc[e], acc[e+1], acc[e+2], acc[e+3]);
}

// ---------------------------------------------------------------------------
// K2: reduce k-chunks + softmax + top1/top2 + per-expert list build.
// Wave = 1 token x 64 expert lanes; 4 tokens per 256-thread block.
// ---------------------------------------------------------------------------
__global__ __launch_bounds__(256) void k_route(
    const float* __restrict__ partial,
    float* __restrict__ p1o, float* __restrict__ p2o,
    int* __restrict__ top1o, int* __restrict__ top2o,
    int* __restrict__ count1, int* __restrict__ count2,
    int* __restrict__ list1, int* __restrict__ list2)
{
    const int tid   = threadIdx.x;
    const int e     = tid & 63;
    const int tl    = tid >> 6;
    const int token = blockIdx.x * 4 + tl;

    float logit = 0.f;
    #pragma unroll
    for (int c = 0; c < NKC; ++c)
        logit += partial[((size_t)c * TOKENS + token) * EXPERTS + e];

    // top-1 argmax across 64 lanes, first-index tie-break
    float bv = logit; int be = e;
    #pragma unroll
    for (int m = 32; m >= 1; m >>= 1) {
        float ov = __shfl_xor(bv, m);
        int   oe = __shfl_xor(be, m);
        if (ov > bv || (ov == bv && oe < be)) { bv = ov; be = oe; }
    }
    const float m1 = bv;
    const int   e1 = be;

    // top-2: argmax excluding e1
    float bv2 = (e == e1) ? -INFINITY : logit;
    int   be2 = (e == e1) ? (1 << 30) : e;
    #pragma unroll
    for (int m = 32; m >= 1; m >>= 1) {
        float ov = __shfl_xor(bv2, m);
        int   oe = __shfl_xor(be2, m);
        if (ov > bv2 || (ov == bv2 && oe < be2)) { bv2 = ov; be2 = oe; }
    }
    const int e2 = be2;

    // softmax denominator (max-subtracted)
    float s = expf(logit - m1);
    #pragma unroll
    for (int m = 32; m >= 1; m >>= 1) s += __shfl_xor(s, m);

    if (e == 0) {
        p1o[token]   = 1.0f / s;
        p2o[token]   = expf(bv2 - m1) / s;
        top1o[token] = e1;
        top2o[token] = e2;
        int s1 = atomicAdd(&count1[e1], 1);
        if (s1 < CAPSLOT) list1[e1 * CAPSLOT + s1] = token;
        int s2 = atomicAdd(&count2[e2], 1);
        if (s2 < CAPSLOT) list2[e2 * CAPSLOT + s2] = token;
    }
}

// ---------------------------------------------------------------------------
// K3: per-expert batch-prioritized ranking -> keep flags.
// rank(t) = #{t' in same list : p1[t'] > p1[t] or (== and t' < t)}
// keep1: rank1 < 512.  keep2: rank2 + (pre-drop top1 count) < 512.
// ---------------------------------------------------------------------------
__global__ __launch_bounds__(256) void k_rank(
    const float* __restrict__ p1,
    const int* __restrict__ count1, const int* __restrict__ count2,
    const int* __restrict__ list1, const int* __restrict__ list2,
    int* __restrict__ keep1, int* __restrict__ keep2)
{
    __shared__ float skey[CAPSLOT];
    __shared__ int   stok[CAPSLOT];

    const int e  = blockIdx.x;
    const int n1 = min(count1[e], CAPSLOT);

    for (int i = threadIdx.x; i < n1; i += 256) {
        int t = list1[e * CAPSLOT + i];
        stok[i] = t;
        skey[i] = p1[t];
    }
    __syncthreads();
    for (int i = threadIdx.x; i < n1; i += 256) {
        const float ki = skey[i];
        const int   ti = stok[i];
        int r = 0;
        for (int j = 0; j < n1; ++j)
            r += (skey[j] > ki || (skey[j] == ki && stok[j] < ti)) ? 1 : 0;
        keep1[ti] = (r < EXPERT_CAPACITY) ? 1 : 0;
    }
    __syncthreads();

    const int n2 = min(count2[e], CAPSLOT);
    for (int i = threadIdx.x; i < n2; i += 256) {
        int t = list2[e * CAPSLOT + i];
        stok[i] = t;
        skey[i] = p1[t];
    }
    __syncthreads();
    for (int i = threadIdx.x; i < n2; i += 256) {
        const float ki = skey[i];
        const int   ti = stok[i];
        int r = n1;                        // offset by pre-drop top-1 count
        for (int j = 0; j < n2; ++j)
            r += (skey[j] > ki || (skey[j] == ki && stok[j] < ti)) ? 1 : 0;
        keep2[ti] = (r < EXPERT_CAPACITY) ? 1 : 0;
    }
}

// ---------------------------------------------------------------------------
// K4: materialize [top_1_mask | gates], coalesced (16 threads per token row).
// ---------------------------------------------------------------------------
__global__ __launch_bounds__(256) void k_out(
    const float* __restrict__ p1, const float* __restrict__ p2,
    const int* __restrict__ top1, const int* __restrict__ top2,
    const int* __restrict__ keep1, const int* __restrict__ keep2,
    float* __restrict__ out)
{
    const int tid   = threadIdx.x;
    const int token = blockIdx.x * 16 + (tid >> 4);
    const int eb    = (tid & 15) * 4;

    const int  k1 = keep1[token];
    const int  k2 = keep2[token];
    const float P1 = k1 ? p1[token] : 0.0f;
    const float P2 = k2 ? p2[token] : 0.0f;
    float denom = fmaxf(P1 + P2, 1.1920929e-07f);   // float32 eps clip
    const float g1 = P1 / denom;
    const float g2 = P2 / denom;
    const int e1 = top1[token];
    const int e2 = top2[token];

    float4 mv, pv;
    mv.x = (k1 && e1 == eb + 0) ? 1.0f : 0.0f;
    mv.y = (k1 && e1 == eb + 1) ? 1.0f : 0.0f;
    mv.z = (k1 && e1 == eb + 2) ? 1.0f : 0.0f;
    mv.w = (k1 && e1 == eb + 3) ? 1.0f : 0.0f;
    pv.x = (k1 && e1 == eb + 0) ? g1 : ((k2 && e2 == eb + 0) ? g2 : 0.0f);
    pv.y = (k1 && e1 == eb + 1) ? g1 : ((k2 && e2 == eb + 1) ? g2 : 0.0f);
    pv.z = (k1 && e1 == eb + 2) ? g1 : ((k2 && e2 == eb + 2) ? g2 : 0.0f);
    pv.w = (k1 && e1 == eb + 3) ? g1 : ((k2 && e2 == eb + 3) ? g2 : 0.0f);

    *(float4*)(out + (size_t)token * EXPERTS + eb) = mv;
    *(float4*)(out + (size_t)TOKENS * EXPERTS + (size_t)token * EXPERTS + eb) = pv;
}

// ---------------------------------------------------------------------------
extern "C" void kernel_launch(void* const* d_in, const int* in_sizes, int n_in,
                              void* d_out, int out_size, void* d_ws, size_t ws_size,
                              hipStream_t stream)
{
    const float* x = (const float*)d_in[0];   // (8,2048,2048) fp32
    const float* W = (const float*)d_in[1];   // (2048,64) fp32
    float* out = (float*)d_out;               // 2 * 16384 * 64 fp32

    // workspace layout (~17.3 MB)
    char* ws = (char*)d_ws;
    float* partial = (float*)ws;                          // NKC*TOKENS*EXPERTS
    float* p1    = partial + (size_t)NKC * TOKENS * EXPERTS;
    float* p2    = p1 + TOKENS;
    int*   top1  = (int*)(p2 + TOKENS);
    int*   top2  = top1 + TOKENS;
    int*   keep1 = top2 + TOKENS;
    int*   keep2 = keep1 + TOKENS;
    int*   count1 = keep2 + TOKENS;                       // EXPERTS
    int*   count2 = count1 + EXPERTS;                     // EXPERTS
    int*   list1  = count2 + EXPERTS;                     // EXPERTS*CAPSLOT
    int*   list2  = list1 + EXPERTS * CAPSLOT;            // EXPERTS*CAPSLOT

    (void)hipMemsetAsync(count1, 0, 2 * EXPERTS * sizeof(int), stream);

    k_logits_partial<<<256 * NKC, 128, 0, stream>>>(x, W, partial);
    k_route<<<TOKENS / 4, 256, 0, stream>>>(
        partial, p1, p2, top1, top2, count1, count2, list1, list2);
    k_rank<<<EXPERTS, 256, 0, stream>>>(
        p1, count1, count2, list1, list2, keep1, keep2);
    k_out<<<TOKENS / 16, 256, 0, stream>>>(
        p1, p2, top1, top2, keep1, keep2, out);
}